// Round 2
// baseline (551.783 us; speedup 1.0000x reference)
//
#include <hip/hip_runtime.h>
#include <math.h>

// Problem constants
#define NPROJ 4112          // P = 2*H*K + H*V + 2*H + UNITS
#define HOFF  0                                  // h_t  : 512*1024
#define COFF  524288                             // C_t  : 512*8*128*128
#define NOFF  67633152                           // n_t  : 512*1024

// ---------------------------------------------------------------------------
// Kernel 1: proj = X0@W0 + X1@W1 + bias     (M=512, N=4112, K=1024 each)
// Tile: BM=64, BN=128, BK=16, 512 threads, 4x4 outputs/thread.
// fp32 loads/staging, fp64 ACCUMULATION (reference parity: np fp64 ref, and
// downstream near-zero-denominator cancellation amplifies proj error ~1e3x).
// ---------------------------------------------------------------------------
__global__ __launch_bounds__(512)
void proj_gemm(const float* __restrict__ X0, const float* __restrict__ X1,
               const float* __restrict__ W0, const float* __restrict__ W1,
               const float* __restrict__ bias, float* __restrict__ proj)
{
    const int N = NPROJ;
    const int K = 1024;
    __shared__ float As[16][68];    // [k][row]
    __shared__ float Bs[16][132];   // [k][col]

    const int tid  = threadIdx.x;
    const int row0 = blockIdx.y * 64;
    const int col0 = blockIdx.x * 128;
    const int tx   = tid & 31;      // 32 col groups (2 cols low + 2 cols high)
    const int ty   = tid >> 5;      // 16 row groups (4 rows)

    double acc[4][4];
#pragma unroll
    for (int i = 0; i < 4; ++i)
#pragma unroll
        for (int j = 0; j < 4; ++j) acc[i][j] = 0.0;

    for (int src = 0; src < 2; ++src) {
        const float* __restrict__ A = src ? X1 : X0;
        const float* __restrict__ W = src ? W1 : W0;
        for (int k0 = 0; k0 < K; k0 += 16) {
            if (tid < 256) {
                const int r  = tid >> 2;
                const int kq = (tid & 3) << 2;
                const float4 a = *(const float4*)(A + (size_t)(row0 + r) * K + k0 + kq);
                As[kq + 0][r] = a.x;
                As[kq + 1][r] = a.y;
                As[kq + 2][r] = a.z;
                As[kq + 3][r] = a.w;
            }
            {
                const int kr = tid >> 5;
                const int nc = (tid & 31) << 2;
                const int gn = col0 + nc;
                float4 bv = make_float4(0.f, 0.f, 0.f, 0.f);
                if (gn < N) bv = *(const float4*)(W + (size_t)(k0 + kr) * N + gn);
                *(float4*)&Bs[kr][nc] = bv;
            }
            __syncthreads();
#pragma unroll
            for (int kk = 0; kk < 16; ++kk) {
                const float4 av = *(const float4*)&As[kk][ty << 2];
                const float2 b0 = *(const float2*)&Bs[kk][tx << 1];
                const float2 b1 = *(const float2*)&Bs[kk][64 + (tx << 1)];
                const double ad[4] = {(double)av.x, (double)av.y, (double)av.z, (double)av.w};
                const double bd[4] = {(double)b0.x, (double)b0.y, (double)b1.x, (double)b1.y};
#pragma unroll
                for (int i = 0; i < 4; ++i)
#pragma unroll
                    for (int j = 0; j < 4; ++j)
                        acc[i][j] = fma(ad[i], bd[j], acc[i][j]);
            }
            __syncthreads();
        }
    }

    // epilogue: + bias (fp64), round to fp32, write
    const int c0 = col0 + (tx << 1);
    const int c1 = c0 + 64;
#pragma unroll
    for (int i = 0; i < 4; ++i) {
        const int row = row0 + (ty << 2) + i;
        if (c0 < N) {
            const float2 w0 = make_float2((float)(acc[i][0] + (double)bias[c0]),
                                          (float)(acc[i][1] + (double)bias[c0 + 1]));
            *(float2*)(proj + (size_t)row * N + c0) = w0;
        }
        if (c1 < N) {
            const float2 w1 = make_float2((float)(acc[i][2] + (double)bias[c1]),
                                          (float)(acc[i][3] + (double)bias[c1 + 1]));
            *(float2*)(proj + (size_t)row * N + c1) = w1;
        }
    }
}

// ---------------------------------------------------------------------------
// Kernel 2: fused mLSTM state update. One block per (b,h) pair (4096 blocks).
// All reduction/cancellation-sensitive math in fp64; fp32 only for streaming
// loads/stores. Still HBM-bound (128 KB C traffic per block).
// ---------------------------------------------------------------------------
__global__ __launch_bounds__(256)
void mlstm_update(const float* __restrict__ proj, const float* __restrict__ C_tm1,
                  const float* __restrict__ n_tm1, float* __restrict__ out)
{
    const int bh = blockIdx.x;
    const int b  = bh >> 3;
    const int h  = bh & 7;
    const int t  = threadIdx.x;
    const float* __restrict__ pr = proj + (size_t)b * NPROJ;

    __shared__ double q_s[128];
    __shared__ double coef_s[128];   // i_g * k[kk]
    __shared__ double prod_s[128];   // n_t[kk] * q[kk]
    __shared__ double red_s[8][128]; // retr partials per k-row-group
    __shared__ double denom_s;

    const double ig = exp((double)pr[3072 + h]);
    const double fg = 1.0 / (1.0 + exp(-(double)pr[3080 + h]));

    if (t < 128) {
        const double qv = (double)pr[h * 128 + t];
        const double kv = (double)pr[1024 + h * 128 + t];
        q_s[t]    = qv;
        const double cf = ig * kv;
        coef_s[t] = cf;
        const double nv = fma(fg, (double)n_tm1[(size_t)b * 1024 + h * 128 + t], cf);
        out[NOFF + (size_t)b * 1024 + h * 128 + t] = (float)nv;
        prod_s[t] = nv * qv;
    }
    __syncthreads();

    const int g = t >> 5;   // k-row group 0..7
    const int s = t & 31;   // v float4 slot 0..31
    const float4* __restrict__ Cin  = (const float4*)(C_tm1 + (size_t)bh * 16384);
    float4*       __restrict__ Cout = (float4*)(out + COFF + (size_t)bh * 16384);
    const float4 vf = *(const float4*)(pr + 2048 + h * 128 + (s << 2));
    const double v0 = (double)vf.x, v1 = (double)vf.y, v2 = (double)vf.z, v3 = (double)vf.w;

    double r0 = 0.0, r1 = 0.0, r2 = 0.0, r3 = 0.0;
#pragma unroll 4
    for (int it = 0; it < 16; ++it) {
        const int kr = (it << 3) + g;
        const float4 c  = Cin[(kr << 5) + s];
        const double cf = coef_s[kr];
        const double qv = q_s[kr];
        const double c0 = fma(fg, (double)c.x, cf * v0);
        const double c1 = fma(fg, (double)c.y, cf * v1);
        const double c2 = fma(fg, (double)c.z, cf * v2);
        const double c3 = fma(fg, (double)c.w, cf * v3);
        float4 cn;
        cn.x = (float)c0; cn.y = (float)c1; cn.z = (float)c2; cn.w = (float)c3;
        Cout[(kr << 5) + s] = cn;
        r0 = fma(c0, qv, r0);
        r1 = fma(c1, qv, r1);
        r2 = fma(c2, qv, r2);
        r3 = fma(c3, qv, r3);
    }
    red_s[g][(s << 2) + 0] = r0;
    red_s[g][(s << 2) + 1] = r1;
    red_s[g][(s << 2) + 2] = r2;
    red_s[g][(s << 2) + 3] = r3;
    __syncthreads();

    // denom = sum_k n_t[k]*q[k] + 1e-8   (fp64: 128 -> 64 fold, wave reduce)
    if (t < 64) {
        double x = prod_s[t] + prod_s[t + 64];
#pragma unroll
        for (int off = 32; off > 0; off >>= 1) x += __shfl_xor(x, off, 64);
        if (t == 0) denom_s = x + 1e-8;
    }
    __syncthreads();

    // final retr reduction over 8 groups + h_t epilogue (threads 0..31)
    if (t < 32) {
        double r[4] = {0.0, 0.0, 0.0, 0.0};
#pragma unroll
        for (int gg = 0; gg < 8; ++gg) {
#pragma unroll
            for (int j = 0; j < 4; ++j) r[j] += red_s[gg][(t << 2) + j];
        }
        const double inv = 1.0 / denom_s;
        const float* oo = pr + 3088 + h * 128 + (t << 2);
        float4 hv;
        hv.x = (float)((1.0 / (1.0 + exp(-(double)oo[0]))) * (r[0] * inv));
        hv.y = (float)((1.0 / (1.0 + exp(-(double)oo[1]))) * (r[1] * inv));
        hv.z = (float)((1.0 / (1.0 + exp(-(double)oo[2]))) * (r[2] * inv));
        hv.w = (float)((1.0 / (1.0 + exp(-(double)oo[3]))) * (r[3] * inv));
        *(float4*)(out + HOFF + (size_t)b * 1024 + h * 128 + (t << 2)) = hv;
    }
}

// ---------------------------------------------------------------------------
extern "C" void kernel_launch(void* const* d_in, const int* in_sizes, int n_in,
                              void* d_out, int out_size, void* d_ws, size_t ws_size,
                              hipStream_t stream)
{
    const float* inputs  = (const float*)d_in[0];   // (512, 1024)
    const float* h_tm1   = (const float*)d_in[1];   // (512, 1024)
    const float* C_tm1   = (const float*)d_in[2];   // (512, 8*128*128)
    const float* n_tm1   = (const float*)d_in[3];   // (512, 8*128)
    const float* kernelW = (const float*)d_in[4];   // (1024, 4112)
    const float* rkernel = (const float*)d_in[5];   // (1024, 4112)
    const float* bias    = (const float*)d_in[6];   // (4112,)
    float* out  = (float*)d_out;
    float* proj = (float*)d_ws;                     // 512*4112 floats = 8.4 MB

    dim3 g1(33, 8);   // ceil(4112/128) x (512/64)
    proj_gemm<<<g1, dim3(512), 0, stream>>>(inputs, h_tm1, kernelW, rkernel, bias, proj);
    mlstm_update<<<dim3(4096), dim3(256), 0, stream>>>(proj, C_tm1, n_tm1, out);
}

// Round 3
// 321.173 us; speedup vs baseline: 1.7180x; 1.7180x over previous
//
#include <hip/hip_runtime.h>
#include <math.h>

// Problem constants
#define NPROJ 4112          // P = 2*H*K + H*V + 2*H + UNITS
#define HOFF  0                                  // h_t  : 512*1024
#define COFF  524288                             // C_t  : 512*8*128*128
#define NOFF  67633152                           // n_t  : 512*1024

// ---------------------------------------------------------------------------
// Kernel 1: proj = X0@W0 + X1@W1 + bias     (M=512, N=4112, K=1024 each)
// Tile: BM=64, BN=64, BK=16, 256 threads, 4x4 outputs/thread.
// fp32 FMA inner loop; every 32 k-terms flushed into fp64 accumulators
// (chunked accumulation: fp32 error * sqrt(32/2048), fp64 across chunks).
// ---------------------------------------------------------------------------
__global__ __launch_bounds__(256)
void proj_gemm(const float* __restrict__ X0, const float* __restrict__ X1,
               const float* __restrict__ W0, const float* __restrict__ W1,
               const float* __restrict__ bias, float* __restrict__ proj)
{
    const int N = NPROJ;
    const int K = 1024;
    __shared__ float As[16][68];    // [k][row]
    __shared__ float Bs[16][68];    // [k][col]

    const int tid  = threadIdx.x;
    const int row0 = blockIdx.y * 64;
    const int col0 = blockIdx.x * 64;
    const int tx   = tid & 15;      // 16 col groups of 4
    const int ty   = tid >> 4;      // 16 row groups of 4

    float  acc32[4][4];
    double acc64[4][4];
#pragma unroll
    for (int i = 0; i < 4; ++i)
#pragma unroll
        for (int j = 0; j < 4; ++j) { acc32[i][j] = 0.f; acc64[i][j] = 0.0; }

    for (int src = 0; src < 2; ++src) {
        const float* __restrict__ A = src ? X1 : X0;
        const float* __restrict__ W = src ? W1 : W0;
        for (int kt = 0; kt < 64; ++kt) {
            const int k0 = kt << 4;
            // stage A tile: 64 rows x 16 k (256 threads, one float4 each)
            {
                const int r  = tid >> 2;
                const int kq = (tid & 3) << 2;
                const float4 a = *(const float4*)(A + (size_t)(row0 + r) * K + k0 + kq);
                As[kq + 0][r] = a.x;
                As[kq + 1][r] = a.y;
                As[kq + 2][r] = a.z;
                As[kq + 3][r] = a.w;
            }
            // stage B tile: 16 k x 64 n (256 threads, one float4 each)
            {
                const int kr = tid >> 4;
                const int nc = (tid & 15) << 2;
                const int gn = col0 + nc;
                float4 bv = make_float4(0.f, 0.f, 0.f, 0.f);
                if (gn < N) bv = *(const float4*)(W + (size_t)(k0 + kr) * N + gn);
                *(float4*)&Bs[kr][nc] = bv;
            }
            __syncthreads();
#pragma unroll
            for (int kk = 0; kk < 16; ++kk) {
                const float4 av = *(const float4*)&As[kk][ty << 2];
                const float4 bv = *(const float4*)&Bs[kk][tx << 2];
                const float aa[4] = {av.x, av.y, av.z, av.w};
                const float bb[4] = {bv.x, bv.y, bv.z, bv.w};
#pragma unroll
                for (int i = 0; i < 4; ++i)
#pragma unroll
                    for (int j = 0; j < 4; ++j)
                        acc32[i][j] = fmaf(aa[i], bb[j], acc32[i][j]);
            }
            __syncthreads();
            // flush fp32 chunk (32 k-terms) into fp64 accumulators
            if (kt & 1) {
#pragma unroll
                for (int i = 0; i < 4; ++i)
#pragma unroll
                    for (int j = 0; j < 4; ++j) {
                        acc64[i][j] += (double)acc32[i][j];
                        acc32[i][j] = 0.f;
                    }
            }
        }
    }

    // epilogue: + bias (fp64), round to fp32, write float4 (N 16-aligned)
    const int c = col0 + (tx << 2);
    if (c < N) {
#pragma unroll
        for (int i = 0; i < 4; ++i) {
            const int row = row0 + (ty << 2) + i;
            float4 w;
            w.x = (float)(acc64[i][0] + (double)bias[c + 0]);
            w.y = (float)(acc64[i][1] + (double)bias[c + 1]);
            w.z = (float)(acc64[i][2] + (double)bias[c + 2]);
            w.w = (float)(acc64[i][3] + (double)bias[c + 3]);
            *(float4*)(proj + (size_t)row * N + c) = w;
        }
    }
}

// ---------------------------------------------------------------------------
// Kernel 2: fused mLSTM state update. One block per (b,h) pair (4096 blocks).
// All reduction/cancellation-sensitive math in fp64; fp32 only for streaming
// loads/stores. HBM-bound (128 KB C traffic per block) — measured ~74 us.
// ---------------------------------------------------------------------------
__global__ __launch_bounds__(256)
void mlstm_update(const float* __restrict__ proj, const float* __restrict__ C_tm1,
                  const float* __restrict__ n_tm1, float* __restrict__ out)
{
    const int bh = blockIdx.x;
    const int b  = bh >> 3;
    const int h  = bh & 7;
    const int t  = threadIdx.x;
    const float* __restrict__ pr = proj + (size_t)b * NPROJ;

    __shared__ double q_s[128];
    __shared__ double coef_s[128];   // i_g * k[kk]
    __shared__ double prod_s[128];   // n_t[kk] * q[kk]
    __shared__ double red_s[8][128]; // retr partials per k-row-group
    __shared__ double denom_s;

    const double ig = exp((double)pr[3072 + h]);
    const double fg = 1.0 / (1.0 + exp(-(double)pr[3080 + h]));

    if (t < 128) {
        const double qv = (double)pr[h * 128 + t];
        const double kv = (double)pr[1024 + h * 128 + t];
        q_s[t]    = qv;
        const double cf = ig * kv;
        coef_s[t] = cf;
        const double nv = fma(fg, (double)n_tm1[(size_t)b * 1024 + h * 128 + t], cf);
        out[NOFF + (size_t)b * 1024 + h * 128 + t] = (float)nv;
        prod_s[t] = nv * qv;
    }
    __syncthreads();

    const int g = t >> 5;   // k-row group 0..7
    const int s = t & 31;   // v float4 slot 0..31
    const float4* __restrict__ Cin  = (const float4*)(C_tm1 + (size_t)bh * 16384);
    float4*       __restrict__ Cout = (float4*)(out + COFF + (size_t)bh * 16384);
    const float4 vf = *(const float4*)(pr + 2048 + h * 128 + (s << 2));
    const double v0 = (double)vf.x, v1 = (double)vf.y, v2 = (double)vf.z, v3 = (double)vf.w;

    double r0 = 0.0, r1 = 0.0, r2 = 0.0, r3 = 0.0;
#pragma unroll 4
    for (int it = 0; it < 16; ++it) {
        const int kr = (it << 3) + g;
        const float4 c  = Cin[(kr << 5) + s];
        const double cf = coef_s[kr];
        const double qv = q_s[kr];
        const double c0 = fma(fg, (double)c.x, cf * v0);
        const double c1 = fma(fg, (double)c.y, cf * v1);
        const double c2 = fma(fg, (double)c.z, cf * v2);
        const double c3 = fma(fg, (double)c.w, cf * v3);
        float4 cn;
        cn.x = (float)c0; cn.y = (float)c1; cn.z = (float)c2; cn.w = (float)c3;
        Cout[(kr << 5) + s] = cn;
        r0 = fma(c0, qv, r0);
        r1 = fma(c1, qv, r1);
        r2 = fma(c2, qv, r2);
        r3 = fma(c3, qv, r3);
    }
    red_s[g][(s << 2) + 0] = r0;
    red_s[g][(s << 2) + 1] = r1;
    red_s[g][(s << 2) + 2] = r2;
    red_s[g][(s << 2) + 3] = r3;
    __syncthreads();

    // denom = sum_k n_t[k]*q[k] + 1e-8   (fp64: 128 -> 64 fold, wave reduce)
    if (t < 64) {
        double x = prod_s[t] + prod_s[t + 64];
#pragma unroll
        for (int off = 32; off > 0; off >>= 1) x += __shfl_xor(x, off, 64);
        if (t == 0) denom_s = x + 1e-8;
    }
    __syncthreads();

    // final retr reduction over 8 groups + h_t epilogue (threads 0..31)
    if (t < 32) {
        double r[4] = {0.0, 0.0, 0.0, 0.0};
#pragma unroll
        for (int gg = 0; gg < 8; ++gg) {
#pragma unroll
            for (int j = 0; j < 4; ++j) r[j] += red_s[gg][(t << 2) + j];
        }
        const double inv = 1.0 / denom_s;
        const float* oo = pr + 3088 + h * 128 + (t << 2);
        float4 hv;
        hv.x = (float)((1.0 / (1.0 + exp(-(double)oo[0]))) * (r[0] * inv));
        hv.y = (float)((1.0 / (1.0 + exp(-(double)oo[1]))) * (r[1] * inv));
        hv.z = (float)((1.0 / (1.0 + exp(-(double)oo[2]))) * (r[2] * inv));
        hv.w = (float)((1.0 / (1.0 + exp(-(double)oo[3]))) * (r[3] * inv));
        *(float4*)(out + HOFF + (size_t)b * 1024 + h * 128 + (t << 2)) = hv;
    }
}

// ---------------------------------------------------------------------------
extern "C" void kernel_launch(void* const* d_in, const int* in_sizes, int n_in,
                              void* d_out, int out_size, void* d_ws, size_t ws_size,
                              hipStream_t stream)
{
    const float* inputs  = (const float*)d_in[0];   // (512, 1024)
    const float* h_tm1   = (const float*)d_in[1];   // (512, 1024)
    const float* C_tm1   = (const float*)d_in[2];   // (512, 8*128*128)
    const float* n_tm1   = (const float*)d_in[3];   // (512, 8*128)
    const float* kernelW = (const float*)d_in[4];   // (1024, 4112)
    const float* rkernel = (const float*)d_in[5];   // (1024, 4112)
    const float* bias    = (const float*)d_in[6];   // (4112,)
    float* out  = (float*)d_out;
    float* proj = (float*)d_ws;                     // 512*4112 floats = 8.4 MB

    dim3 g1(65, 8);   // ceil(4112/64) x (512/64)
    proj_gemm<<<g1, dim3(256), 0, stream>>>(inputs, h_tm1, kernelW, rkernel, bias, proj);
    mlstm_update<<<dim3(4096), dim3(256), 0, stream>>>(proj, C_tm1, n_tm1, out);
}